// Round 1
// baseline (283.605 us; speedup 1.0000x reference)
//
#include <hip/hip_runtime.h>
#include <math.h>

#define EPSB 1e-5f

constexpr int N_ = 64, C_ = 256, T_ = 64, V_ = 25, C4_ = 64;
constexpr int NC = N_ * C_;   // 16384
constexpr int TV = T_ * V_;   // 1600

// ---------------- K1: pooled[nc][t] = mean_v x[nc][t][v] ----------------
// 4 rows per block; coalesced LDS stage, then 256 threads reduce 25 each.
__global__ __launch_bounds__(256) void k_pool(const float* __restrict__ x,
                                              float* __restrict__ pooled) {
    __shared__ float xs[4 * TV];
    const int b = blockIdx.x;
    const float* xp = x + (size_t)b * (4 * TV);
    for (int e = threadIdx.x; e < 4 * TV; e += 256) xs[e] = xp[e];
    __syncthreads();
    float s = 0.f;
    const int base = threadIdx.x * V_;   // stride-25 words: 2 lanes/bank, free
#pragma unroll
    for (int v = 0; v < V_; ++v) s += xs[base + v];
    pooled[(size_t)b * 256 + threadIdx.x] = s * (1.0f / 25.0f);
}

// ---------------- K2: G branch (MLP + BN + ReLU + softmax -> kern) -------
// Wave-autonomous: lane j holds Wg1 rows j and j+64 in registers.
__global__ __launch_bounds__(256) void k_gbranch(
    const float* __restrict__ pooled, const float* __restrict__ Wg1,
    const float* __restrict__ g1, const float* __restrict__ b1,
    const float* __restrict__ m1, const float* __restrict__ v1,
    const float* __restrict__ Wg2, float* __restrict__ kern,
    int rows_per_wave) {
    const int lane = threadIdx.x & 63;
    const int gw = blockIdx.x * (blockDim.x >> 6) + (threadIdx.x >> 6);
    const int j0 = lane, j1 = lane + 64;

    float w0[T_], w1[T_];
#pragma unroll
    for (int t = 0; t < T_; ++t) {
        w0[t] = Wg1[j0 * T_ + t];
        w1[t] = Wg1[j1 * T_ + t];
    }
    const float s0 = g1[j0] * rsqrtf(v1[j0] + EPSB);
    const float s1 = g1[j1] * rsqrtf(v1[j1] + EPSB);
    const float c0 = b1[j0] - m1[j0] * s0;
    const float c1 = b1[j1] - m1[j1] * s1;
    const float wa0 = Wg2[0 * 128 + j0], wa1 = Wg2[0 * 128 + j1];
    const float wb0 = Wg2[1 * 128 + j0], wb1 = Wg2[1 * 128 + j1];
    const float wc0 = Wg2[2 * 128 + j0], wc1 = Wg2[2 * 128 + j1];

    for (int rr = 0; rr < rows_per_wave; ++rr) {
        const int row = gw * rows_per_wave + rr;
        const float pv = pooled[(size_t)row * T_ + lane];
        float h0 = 0.f, h1 = 0.f;
#pragma unroll
        for (int t = 0; t < T_; ++t) {
            const float pt = __shfl(pv, t);
            h0 = fmaf(w0[t], pt, h0);
            h1 = fmaf(w1[t], pt, h1);
        }
        h0 = fmaxf(fmaf(h0, s0, c0), 0.f);
        h1 = fmaxf(fmaf(h1, s1, c1), 0.f);
        float p0 = wa0 * h0 + wa1 * h1;
        float p1 = wb0 * h0 + wb1 * h1;
        float p2 = wc0 * h0 + wc1 * h1;
#pragma unroll
        for (int off = 32; off > 0; off >>= 1) {
            p0 += __shfl_xor(p0, off);
            p1 += __shfl_xor(p1, off);
            p2 += __shfl_xor(p2, off);
        }
        const float mx = fmaxf(p0, fmaxf(p1, p2));
        const float e0 = expf(p0 - mx), e1 = expf(p1 - mx), e2 = expf(p2 - mx);
        const float inv = 1.0f / (e0 + e1 + e2);
        if (lane < 3) {
            const float val = (lane == 0) ? e0 : (lane == 1) ? e1 : e2;
            kern[(size_t)row * 3 + lane] = val * inv;
        }
    }
}

// ---------------- K3: L branch (conv1d K=3 + BN + ReLU + conv1d k=1 + sigmoid)
// grid = n * (T/16); per-block: pooled slice (+halo) in LDS.
__global__ __launch_bounds__(256) void k_lbranch(
    const float* __restrict__ pooled, const float* __restrict__ WL1,
    const float* __restrict__ g2, const float* __restrict__ b2,
    const float* __restrict__ m2, const float* __restrict__ v2,
    const float* __restrict__ WL2, float* __restrict__ act) {
    __shared__ float ps[C_][18];     // pooled[n][i][t0-1 .. t0+16]
    __shared__ float a1s[C4_][17];   // padded to break bank alignment
    const int nb = blockIdx.x;
    const int n = nb >> 2;
    const int t0 = (nb & 3) * 16;
    const float* pn = pooled + (size_t)n * C_ * T_;

    for (int e = threadIdx.x; e < C_ * 18; e += 256) {
        const int i = e / 18, tt = e % 18;
        const int gt = t0 - 1 + tt;
        ps[i][tt] = (gt >= 0 && gt < T_) ? pn[i * T_ + gt] : 0.f;
    }
    __syncthreads();

    // conv1: each thread -> (cc, 4 consecutive t)
    const int cc = threadIdx.x >> 2;
    const int tt0 = (threadIdx.x & 3) * 4;
    float a0 = 0.f, a1 = 0.f, a2 = 0.f, a3 = 0.f;
    const float* wrow = WL1 + (size_t)cc * C_ * 3;
    for (int i = 0; i < C_; ++i) {
        const float wk0 = wrow[i * 3 + 0];
        const float wk1 = wrow[i * 3 + 1];
        const float wk2 = wrow[i * 3 + 2];
        const float pA = ps[i][tt0 + 0], pB = ps[i][tt0 + 1];
        const float pC = ps[i][tt0 + 2], pD = ps[i][tt0 + 3];
        const float pE = ps[i][tt0 + 4], pF = ps[i][tt0 + 5];
        a0 = fmaf(wk0, pA, fmaf(wk1, pB, fmaf(wk2, pC, a0)));
        a1 = fmaf(wk0, pB, fmaf(wk1, pC, fmaf(wk2, pD, a1)));
        a2 = fmaf(wk0, pC, fmaf(wk1, pD, fmaf(wk2, pE, a2)));
        a3 = fmaf(wk0, pD, fmaf(wk1, pE, fmaf(wk2, pF, a3)));
    }
    const float sc = g2[cc] * rsqrtf(v2[cc] + EPSB);
    const float sh = b2[cc] - m2[cc] * sc;
    a1s[cc][tt0 + 0] = fmaxf(fmaf(a0, sc, sh), 0.f);
    a1s[cc][tt0 + 1] = fmaxf(fmaf(a1, sc, sh), 0.f);
    a1s[cc][tt0 + 2] = fmaxf(fmaf(a2, sc, sh), 0.f);
    a1s[cc][tt0 + 3] = fmaxf(fmaf(a3, sc, sh), 0.f);
    __syncthreads();

    // conv2 (k=1) + sigmoid: thread = output channel c, 16 t each
    const int c = threadIdx.x;
    float o[16];
#pragma unroll
    for (int q = 0; q < 16; ++q) o[q] = 0.f;
    const float* w2 = WL2 + (size_t)c * C4_;
    for (int i = 0; i < C4_; ++i) {
        const float w = w2[i];
#pragma unroll
        for (int q = 0; q < 16; ++q) o[q] = fmaf(w, a1s[i][q], o[q]);  // broadcast reads
    }
    float* arow = act + ((size_t)n * C_ + c) * T_ + t0;
#pragma unroll
    for (int q = 0; q < 16; ++q) arow[q] = 1.0f / (1.0f + expf(-o[q]));
}

// ---------------- K4: out = x + sum_k kern_k * (x*act)[t+k-1] ------------
__global__ __launch_bounds__(256) void k_final(const float* __restrict__ x,
                                               const float* __restrict__ act,
                                               const float* __restrict__ kern,
                                               float* __restrict__ out) {
    __shared__ float xs[TV];
    __shared__ float as[T_ + 2];   // act[t-1..t+64], zero-padded
    const int row = blockIdx.x;
    const float* xr = x + (size_t)row * TV;
    float* outr = out + (size_t)row * TV;
    for (int e = threadIdx.x; e < TV; e += 256) xs[e] = xr[e];
    if (threadIdx.x < T_ + 2) {
        const int t = (int)threadIdx.x - 1;
        as[threadIdx.x] = (t >= 0 && t < T_) ? act[(size_t)row * T_ + t] : 0.f;
    }
    const float k0 = kern[(size_t)row * 3 + 0];
    const float k1 = kern[(size_t)row * 3 + 1];
    const float k2 = kern[(size_t)row * 3 + 2];
    __syncthreads();
    for (int e = threadIdx.x; e < TV; e += 256) {
        const int t = e / 25;
        const float xc = xs[e];
        const float xm = (t > 0)  ? xs[e - 25] : 0.f;
        const float xq = (t < 63) ? xs[e + 25] : 0.f;
        outr[e] = xc + k0 * xm * as[t] + k1 * xc * as[t + 1] + k2 * xq * as[t + 2];
    }
}

extern "C" void kernel_launch(void* const* d_in, const int* in_sizes, int n_in,
                              void* d_out, int out_size, void* d_ws, size_t ws_size,
                              hipStream_t stream) {
    const float* x   = (const float*)d_in[0];
    const float* Wg1 = (const float*)d_in[1];
    const float* g1  = (const float*)d_in[2];
    const float* b1  = (const float*)d_in[3];
    const float* m1  = (const float*)d_in[4];
    const float* v1  = (const float*)d_in[5];
    const float* Wg2 = (const float*)d_in[6];
    const float* WL1 = (const float*)d_in[7];
    const float* g2  = (const float*)d_in[8];
    const float* b2  = (const float*)d_in[9];
    const float* m2  = (const float*)d_in[10];
    const float* v2  = (const float*)d_in[11];
    const float* WL2 = (const float*)d_in[12];
    float* out = (float*)d_out;

    float* ws = (float*)d_ws;
    float* pooled = ws;                    // NC*T = 1,048,576 floats
    float* act    = ws + (size_t)NC * T_;  // 1,048,576 floats
    float* kern   = ws + (size_t)2 * NC * T_;  // NC*3 floats

    k_pool   <<<NC / 4, 256, 0, stream>>>(x, pooled);
    k_gbranch<<<512,    256, 0, stream>>>(pooled, Wg1, g1, b1, m1, v1, Wg2, kern, 8);
    k_lbranch<<<N_ * 4, 256, 0, stream>>>(pooled, WL1, g2, b2, m2, v2, WL2, act);
    k_final  <<<NC,     256, 0, stream>>>(x, act, kern, out);
}

// Round 2
// 279.287 us; speedup vs baseline: 1.0155x; 1.0155x over previous
//
#include <hip/hip_runtime.h>
#include <math.h>

#define EPSB 1e-5f

constexpr int N_ = 64, C_ = 256, T_ = 64, V_ = 25, C4_ = 64;
constexpr int NC = N_ * C_;   // 16384
constexpr int TV = T_ * V_;   // 1600

// ---------------- K1: pooled[nc][t] = mean_v x[nc][t][v] ----------------
// 4 rows/block; float4 LDS stage (16B/lane), 256 threads reduce 25 each.
__global__ __launch_bounds__(256) void k_pool(const float* __restrict__ x,
                                              float* __restrict__ pooled) {
    __shared__ float xs[4 * TV];
    const int b = blockIdx.x;
    const float4* xp4 = (const float4*)(x + (size_t)b * (4 * TV));
    float4* xs4 = (float4*)xs;
    for (int f = threadIdx.x; f < TV; f += 256) xs4[f] = xp4[f];   // 4*TV/4 = 1600
    __syncthreads();
    float s = 0.f;
    const int base = threadIdx.x * V_;   // stride-25 words: 2 lanes/bank, free
#pragma unroll
    for (int v = 0; v < V_; ++v) s += xs[base + v];
    pooled[(size_t)b * 256 + threadIdx.x] = s * (1.0f / 25.0f);
}

// ---------------- K2: G branch (MLP + BN + ReLU + softmax -> kern) -------
// Weights staged LDS-transposed (conflict-free per-lane fragment loads);
// pooled row read through wave-uniform pointer (scalar loads + VALU fma).
__global__ __launch_bounds__(256) void k_gbranch(
    const float* __restrict__ pooled, const float* __restrict__ Wg1,
    const float* __restrict__ g1, const float* __restrict__ b1,
    const float* __restrict__ m1, const float* __restrict__ v1,
    const float* __restrict__ Wg2, float* __restrict__ kern) {
    __shared__ float Wt[T_ * 130];   // Wt[t][j], j=0..127, pad 130
    // stage transposed: consecutive e -> t fast -> stride-130 writes, no conflict
    for (int e = threadIdx.x; e < 128 * T_; e += 256) {
        const int j = e >> 6, t = e & 63;
        Wt[t * 130 + j] = Wg1[e];
    }
    __syncthreads();

    const int lane = threadIdx.x & 63;
    const int gw = blockIdx.x * 4 + (threadIdx.x >> 6);
    const int j0 = lane, j1 = lane + 64;

    float w0[T_], w1[T_];
#pragma unroll
    for (int t = 0; t < T_; ++t) {
        w0[t] = Wt[t * 130 + j0];       // lanes consecutive: conflict-free
        w1[t] = Wt[t * 130 + j1];
    }
    const float s0 = g1[j0] * rsqrtf(v1[j0] + EPSB);
    const float s1 = g1[j1] * rsqrtf(v1[j1] + EPSB);
    const float c0 = b1[j0] - m1[j0] * s0;
    const float c1 = b1[j1] - m1[j1] * s1;
    const float wa0 = Wg2[0 * 128 + j0], wa1 = Wg2[0 * 128 + j1];
    const float wb0 = Wg2[1 * 128 + j0], wb1 = Wg2[1 * 128 + j1];
    const float wc0 = Wg2[2 * 128 + j0], wc1 = Wg2[2 * 128 + j1];

    for (int rr = 0; rr < 8; ++rr) {
        const int row = __builtin_amdgcn_readfirstlane(gw * 8 + rr);
        const float* __restrict__ prow = pooled + (size_t)row * T_;
        float h0 = 0.f, h1 = 0.f;
#pragma unroll
        for (int t = 0; t < T_; ++t) {
            const float pt = prow[t];   // wave-uniform -> scalar load
            h0 = fmaf(w0[t], pt, h0);
            h1 = fmaf(w1[t], pt, h1);
        }
        h0 = fmaxf(fmaf(h0, s0, c0), 0.f);
        h1 = fmaxf(fmaf(h1, s1, c1), 0.f);
        float p0 = wa0 * h0 + wa1 * h1;
        float p1 = wb0 * h0 + wb1 * h1;
        float p2 = wc0 * h0 + wc1 * h1;
#pragma unroll
        for (int off = 32; off > 0; off >>= 1) {
            p0 += __shfl_xor(p0, off);
            p1 += __shfl_xor(p1, off);
            p2 += __shfl_xor(p2, off);
        }
        const float mx = fmaxf(p0, fmaxf(p1, p2));
        const float e0 = expf(p0 - mx), e1 = expf(p1 - mx), e2 = expf(p2 - mx);
        const float inv = 1.0f / (e0 + e1 + e2);
        if (lane < 3) {
            const float val = (lane == 0) ? e0 : (lane == 1) ? e1 : e2;
            kern[(size_t)row * 3 + lane] = val * inv;
        }
    }
}

// ---------------- K3a: conv1(K=3) + BN + ReLU -> a1[n][cc][t] ------------
// 256 blocks x 4 waves; wave owns a wave-uniform cc-quad (scalar weight
// loads), lane = t. pooled[n] staged in LDS with zero halo cols.
__global__ __launch_bounds__(256) void kL1(
    const float* __restrict__ pooled, const float* __restrict__ WL1,
    const float* __restrict__ g2, const float* __restrict__ b2,
    const float* __restrict__ m2, const float* __restrict__ v2,
    float* __restrict__ a1) {
    __shared__ float ps[C_ * 66];      // ps[i][0]=0, ps[i][1+t], ps[i][65]=0
    const int n = blockIdx.x >> 2;
    const int bq = blockIdx.x & 3;
    const int w = threadIdx.x >> 6;
    const int t = threadIdx.x & 63;
    const float* pn = pooled + (size_t)n * (C_ * T_);

    for (int e = threadIdx.x; e < C_ * T_; e += 256) {
        const int i = e >> 6, tt = e & 63;
        ps[i * 66 + 1 + tt] = pn[e];
    }
    {   // zero halo columns
        const int i = threadIdx.x;
        ps[i * 66] = 0.f;
        ps[i * 66 + 65] = 0.f;
    }
    __syncthreads();

    const int ccb = __builtin_amdgcn_readfirstlane(bq * 16 + w * 4);
    const float* __restrict__ wb = WL1 + (size_t)ccb * (C_ * 3);
    float a0 = 0.f, a1v = 0.f, a2 = 0.f, a3 = 0.f;
#pragma unroll 4
    for (int i = 0; i < C_; ++i) {
        const float pm = ps[i * 66 + t];        // pooled[t-1] (0 at edge)
        const float pc = ps[i * 66 + 1 + t];    // pooled[t]
        const float pp = ps[i * 66 + 2 + t];    // pooled[t+1] (0 at edge)
        a0 = fmaf(wb[0 * 768 + i * 3 + 0], pm, fmaf(wb[0 * 768 + i * 3 + 1], pc, fmaf(wb[0 * 768 + i * 3 + 2], pp, a0)));
        a1v = fmaf(wb[1 * 768 + i * 3 + 0], pm, fmaf(wb[1 * 768 + i * 3 + 1], pc, fmaf(wb[1 * 768 + i * 3 + 2], pp, a1v)));
        a2 = fmaf(wb[2 * 768 + i * 3 + 0], pm, fmaf(wb[2 * 768 + i * 3 + 1], pc, fmaf(wb[2 * 768 + i * 3 + 2], pp, a2)));
        a3 = fmaf(wb[3 * 768 + i * 3 + 0], pm, fmaf(wb[3 * 768 + i * 3 + 1], pc, fmaf(wb[3 * 768 + i * 3 + 2], pp, a3)));
    }
    float* ab = a1 + ((size_t)n * C4_ + ccb) * T_ + t;
    const float acc[4] = {a0, a1v, a2, a3};
#pragma unroll
    for (int j = 0; j < 4; ++j) {
        const int cc = ccb + j;
        const float sc = g2[cc] * rsqrtf(v2[cc] + EPSB);
        const float sh = b2[cc] - m2[cc] * sc;
        ab[j * T_] = fmaxf(fmaf(acc[j], sc, sh), 0.f);
    }
}

// ---------------- K3b: conv2(k=1) + sigmoid -> act[n][c][t] --------------
// 1024 blocks x 4 waves; wave owns a wave-uniform c-quad (scalar weights),
// lane = t, a1 rows read coalesced from L2.
__global__ __launch_bounds__(256) void kL2(
    const float* __restrict__ a1, const float* __restrict__ WL2,
    float* __restrict__ act) {
    const int n = blockIdx.x >> 4;
    const int bq = blockIdx.x & 15;
    const int w = threadIdx.x >> 6;
    const int t = threadIdx.x & 63;
    const int cb = __builtin_amdgcn_readfirstlane(bq * 16 + w * 4);
    const float* __restrict__ an = a1 + (size_t)n * (C4_ * T_);
    const float* __restrict__ w2 = WL2 + (size_t)cb * C4_;
    float o0 = 0.f, o1 = 0.f, o2 = 0.f, o3 = 0.f;
#pragma unroll 4
    for (int i = 0; i < C4_; ++i) {
        const float av = an[i * T_ + t];   // coalesced, L2-hit
        o0 = fmaf(w2[0 * C4_ + i], av, o0);
        o1 = fmaf(w2[1 * C4_ + i], av, o1);
        o2 = fmaf(w2[2 * C4_ + i], av, o2);
        o3 = fmaf(w2[3 * C4_ + i], av, o3);
    }
    float* ar = act + ((size_t)n * C_ + cb) * T_ + t;
    ar[0 * T_] = 1.0f / (1.0f + expf(-o0));
    ar[1 * T_] = 1.0f / (1.0f + expf(-o1));
    ar[2 * T_] = 1.0f / (1.0f + expf(-o2));
    ar[3 * T_] = 1.0f / (1.0f + expf(-o3));
}

// ---------------- K4: out = x + sum_k kern_k * (x*act)[t+k-1] ------------
__global__ __launch_bounds__(256) void k_final(const float* __restrict__ x,
                                               const float* __restrict__ act,
                                               const float* __restrict__ kern,
                                               float* __restrict__ out) {
    __shared__ float xs[TV];
    __shared__ float as[T_ + 2];   // act[t-1..t+64], zero-padded
    const int row = blockIdx.x;
    const float4* xr4 = (const float4*)(x + (size_t)row * TV);
    float4* outr4 = (float4*)(out + (size_t)row * TV);
    float4* xs4 = (float4*)xs;
    for (int f = threadIdx.x; f < TV / 4; f += 256) xs4[f] = xr4[f];
    if (threadIdx.x < T_ + 2) {
        const int t = (int)threadIdx.x - 1;
        as[threadIdx.x] = (t >= 0 && t < T_) ? act[(size_t)row * T_ + t] : 0.f;
    }
    const float k0 = kern[(size_t)row * 3 + 0];
    const float k1 = kern[(size_t)row * 3 + 1];
    const float k2 = kern[(size_t)row * 3 + 2];
    __syncthreads();
    for (int f = threadIdx.x; f < TV / 4; f += 256) {
        float r[4];
#pragma unroll
        for (int q = 0; q < 4; ++q) {
            const int e = f * 4 + q;
            const int t = e / 25;
            const float xc = xs[e];
            const float xm = (t > 0)  ? xs[e - 25] : 0.f;
            const float xq = (t < 63) ? xs[e + 25] : 0.f;
            r[q] = xc + k0 * xm * as[t] + k1 * xc * as[t + 1] + k2 * xq * as[t + 2];
        }
        outr4[f] = make_float4(r[0], r[1], r[2], r[3]);
    }
}

extern "C" void kernel_launch(void* const* d_in, const int* in_sizes, int n_in,
                              void* d_out, int out_size, void* d_ws, size_t ws_size,
                              hipStream_t stream) {
    const float* x   = (const float*)d_in[0];
    const float* Wg1 = (const float*)d_in[1];
    const float* g1  = (const float*)d_in[2];
    const float* b1  = (const float*)d_in[3];
    const float* m1  = (const float*)d_in[4];
    const float* v1  = (const float*)d_in[5];
    const float* Wg2 = (const float*)d_in[6];
    const float* WL1 = (const float*)d_in[7];
    const float* g2  = (const float*)d_in[8];
    const float* b2  = (const float*)d_in[9];
    const float* m2  = (const float*)d_in[10];
    const float* v2  = (const float*)d_in[11];
    const float* WL2 = (const float*)d_in[12];
    float* out = (float*)d_out;

    float* ws = (float*)d_ws;
    float* pooled = ws;                          // NC*T floats (4 MB)
    float* act    = ws + (size_t)NC * T_;        // NC*T floats (4 MB)
    float* kern   = ws + (size_t)2 * NC * T_;    // NC*3 floats
    float* a1buf  = ws + (size_t)2 * NC * T_ + (size_t)NC * 4;  // N*64*64 floats (1 MB)

    k_pool   <<<NC / 4, 256, 0, stream>>>(x, pooled);
    k_gbranch<<<512,    256, 0, stream>>>(pooled, Wg1, g1, b1, m1, v1, Wg2, kern);
    kL1      <<<N_ * 4, 256, 0, stream>>>(pooled, WL1, g2, b2, m2, v2, a1buf);
    kL2      <<<N_ * 16,256, 0, stream>>>(a1buf, WL2, act);
    k_final  <<<NC,     256, 0, stream>>>(x, act, kern, out);
}